// Round 2
// baseline (2250.384 us; speedup 1.0000x reference)
//
#include <hip/hip_runtime.h>
#include <hip/hip_bf16.h>

#define N_B   4
#define LSEQ  2048
#define DM    1024
#define NH    16
#define HD    64
#define MROWS (N_B * LSEQ)   // 8192

// C[M,N] = act(A[M,K] @ W[K,N] + bias[N]); ACT=1 -> elu(x)+1
template <int ACT>
__global__ __launch_bounds__(256) void gemm_bias_act(
    const float* __restrict__ A, const float* __restrict__ W,
    const float* __restrict__ bias, float* __restrict__ C,
    int M, int K, int N)
{
    __shared__ float As[16][65];
    __shared__ float Bs[16][65];
    const int tx = threadIdx.x & 15;   // n direction
    const int ty = threadIdx.x >> 4;   // m direction
    const int m0 = blockIdx.x * 64;
    const int n0 = blockIdx.y * 64;

    float acc[4][4] = {};

    for (int k0 = 0; k0 < K; k0 += 16) {
        // A tile: 64 rows x 16 k
        #pragma unroll
        for (int r = 0; r < 4; ++r) {
            int e = r * 256 + threadIdx.x;
            int m = e >> 4, kk = e & 15;
            As[kk][m] = A[(size_t)(m0 + m) * K + k0 + kk];
        }
        // B tile: 16 k x 64 cols
        #pragma unroll
        for (int r = 0; r < 4; ++r) {
            int e = r * 256 + threadIdx.x;
            int n = e & 63, kk = e >> 6;
            Bs[kk][n] = W[(size_t)(k0 + kk) * N + n0 + n];
        }
        __syncthreads();
        #pragma unroll
        for (int kk = 0; kk < 16; ++kk) {
            float a[4], b[4];
            #pragma unroll
            for (int i = 0; i < 4; ++i) a[i] = As[kk][ty * 4 + i];
            #pragma unroll
            for (int j = 0; j < 4; ++j) b[j] = Bs[kk][tx * 4 + j];
            #pragma unroll
            for (int i = 0; i < 4; ++i)
                #pragma unroll
                for (int j = 0; j < 4; ++j)
                    acc[i][j] += a[i] * b[j];
        }
        __syncthreads();
    }

    #pragma unroll
    for (int i = 0; i < 4; ++i) {
        int m = m0 + ty * 4 + i;
        #pragma unroll
        for (int j = 0; j < 4; ++j) {
            int n = n0 + tx * 4 + j;
            float x = acc[i][j] + bias[n];
            if (ACT) x = (x > 0.f) ? (x + 1.f) : __expf(x);
            C[(size_t)m * N + n] = x;
        }
    }
}

// Causal linear attention scan. One block per (n,h). 256 threads:
// lane k = tid&63 (output/value feature), dg = tid>>6 (one of 4 waves, each
// owning 16 of the 64 d-features). Thread holds S[dg*16+i][k], i in [0,16).
#define CH 32
__global__ __launch_bounds__(256) void attn_scan(
    const float* __restrict__ qp, const float* __restrict__ kp,
    const float* __restrict__ v, float* __restrict__ att)
{
    __shared__ float qb[CH][HD];
    __shared__ float kb[CH][HD];
    __shared__ float vb[CH][HD];
    __shared__ float red[4][HD];

    const int b = blockIdx.x;        // 0..63
    const int n = b >> 4, h = b & 15;
    const int k = threadIdx.x & 63;
    const int dg = threadIdx.x >> 6; // wave-uniform

    float S[16];
    #pragma unroll
    for (int i = 0; i < 16; ++i) S[i] = 0.f;
    float Z = 0.f; // running cumsum of qp[k] (used by wave 0 only)

    const size_t base = (size_t)n * LSEQ * DM + (size_t)h * HD;

    for (int c0 = 0; c0 < LSEQ; c0 += CH) {
        __syncthreads();
        for (int e = threadIdx.x; e < CH * HD; e += 256) {
            int s = e >> 6, c = e & 63;
            size_t g = base + (size_t)(c0 + s) * DM + c;
            qb[s][c] = qp[g];
            kb[s][c] = kp[g];
            vb[s][c] = v[g];
        }
        __syncthreads();
        for (int s = 0; s < CH; ++s) {
            float vk = vb[s][k];
            float acc = 0.f;
            #pragma unroll
            for (int i = 0; i < 16; ++i) {
                float kd = kb[s][dg * 16 + i]; // wave-uniform LDS broadcast
                float qd = qb[s][dg * 16 + i];
                S[i] += kd * vk;
                acc += qd * S[i];
            }
            red[dg][k] = acc;
            __syncthreads();
            if (dg == 0) {
                float sum = red[0][k] + red[1][k] + red[2][k] + red[3][k];
                Z += qb[s][k];
                att[base + (size_t)(c0 + s) * DM + k] = sum / Z;
            }
            __syncthreads();
        }
    }
}

extern "C" void kernel_launch(void* const* d_in, const int* in_sizes, int n_in,
                              void* d_out, int out_size, void* d_ws, size_t ws_size,
                              hipStream_t stream)
{
    const float* queries = (const float*)d_in[0];
    const float* keys    = (const float*)d_in[1];
    const float* values  = (const float*)d_in[2];
    const float* Wq = (const float*)d_in[3];
    const float* bq = (const float*)d_in[4];
    const float* Wk = (const float*)d_in[5];
    const float* bk = (const float*)d_in[6];
    const float* Wv = (const float*)d_in[7];
    const float* bv = (const float*)d_in[8];
    const float* Wo = (const float*)d_in[9];
    const float* bo = (const float*)d_in[10];
    float* out = (float*)d_out;

    const size_t elems = (size_t)MROWS * DM;
    float* qp  = (float*)d_ws;
    float* kp  = qp + elems;
    float* vv  = kp + elems;
    float* att = vv + elems;

    dim3 gblk(MROWS / 64, DM / 64);
    gemm_bias_act<1><<<gblk, 256, 0, stream>>>(queries, Wq, bq, qp, MROWS, DM, DM);
    gemm_bias_act<1><<<gblk, 256, 0, stream>>>(keys,    Wk, bk, kp, MROWS, DM, DM);
    gemm_bias_act<0><<<gblk, 256, 0, stream>>>(values,  Wv, bv, vv, MROWS, DM, DM);

    attn_scan<<<N_B * NH, 256, 0, stream>>>(qp, kp, vv, att);

    gemm_bias_act<0><<<gblk, 256, 0, stream>>>(att, Wo, bo, out, MROWS, DM, DM);
}

// Round 4
// 1592.265 us; speedup vs baseline: 1.4133x; 1.4133x over previous
//
#include <hip/hip_runtime.h>
#include <hip/hip_bf16.h>

typedef __hip_bfloat16 bf16;

#define N_B   4
#define LSEQ  2048
#define DM    1024
#define NH    16
#define HD    64
#define MROWS (N_B * LSEQ)   // 8192
#define TCH   64
#define NC    (LSEQ / TCH)   // 32 chunks

__device__ __forceinline__ float b2f(bf16 x){ return __bfloat162float(x); }
__device__ __forceinline__ bf16  f2b(float x){ return __float2bfloat16(x); }
__device__ __forceinline__ float u2f(unsigned short u){ return __uint_as_float(((unsigned)u) << 16); }
__device__ __forceinline__ unsigned short f2u(float x){
    bf16 h = __float2bfloat16(x);
    return *reinterpret_cast<unsigned short*>(&h);
}

__device__ __forceinline__ float ldf(const float* p){ return *p; }
__device__ __forceinline__ float ldf(const bf16*  p){ return b2f(*p); }
__device__ __forceinline__ void  stf(float* p, float x){ *p = x; }
__device__ __forceinline__ void  stf(bf16*  p, float x){ *p = f2b(x); }

// acc[a][.] += sum_j X[a].comp(j) * Y[j][.]
__device__ __forceinline__ void fma44(float4 acc[4], const float4 X[4], const float4 Y[4]){
    #pragma unroll
    for (int a = 0; a < 4; ++a){
        float4 xa = X[a];
        { float s = xa.x; float4 yj = Y[0];
          acc[a].x += s*yj.x; acc[a].y += s*yj.y; acc[a].z += s*yj.z; acc[a].w += s*yj.w; }
        { float s = xa.y; float4 yj = Y[1];
          acc[a].x += s*yj.x; acc[a].y += s*yj.y; acc[a].z += s*yj.z; acc[a].w += s*yj.w; }
        { float s = xa.z; float4 yj = Y[2];
          acc[a].x += s*yj.x; acc[a].y += s*yj.y; acc[a].z += s*yj.z; acc[a].w += s*yj.w; }
        { float s = xa.w; float4 yj = Y[3];
          acc[a].x += s*yj.x; acc[a].y += s*yj.y; acc[a].z += s*yj.z; acc[a].w += s*yj.w; }
    }
}

// ---------------------------------------------------------------------------
// GEMM: C[M,N] = act(A[M,K] @ W[K,N] + bias[N]); ACT=1 -> elu(x)+1
template <int ACT, typename TI, typename TO>
__global__ __launch_bounds__(256) void gemm_bias_act(
    const TI* __restrict__ A, const float* __restrict__ W,
    const float* __restrict__ bias, TO* __restrict__ C,
    int M, int K, int N)
{
    __shared__ float As[16][65];
    __shared__ float Bs[16][65];
    const int tx = threadIdx.x & 15;
    const int ty = threadIdx.x >> 4;
    const int m0 = blockIdx.x * 64;
    const int n0 = blockIdx.y * 64;

    float acc[4][4] = {};

    for (int k0 = 0; k0 < K; k0 += 16) {
        #pragma unroll
        for (int r = 0; r < 4; ++r) {
            int e = r * 256 + threadIdx.x;
            int m = e >> 4, kk = e & 15;
            As[kk][m] = ldf(&A[(size_t)(m0 + m) * K + k0 + kk]);
        }
        #pragma unroll
        for (int r = 0; r < 4; ++r) {
            int e = r * 256 + threadIdx.x;
            int n = e & 63, kk = e >> 6;
            Bs[kk][n] = W[(size_t)(k0 + kk) * N + n0 + n];
        }
        __syncthreads();
        #pragma unroll
        for (int kk = 0; kk < 16; ++kk) {
            float a[4], b[4];
            #pragma unroll
            for (int i = 0; i < 4; ++i) a[i] = As[kk][ty * 4 + i];
            #pragma unroll
            for (int j = 0; j < 4; ++j) b[j] = Bs[kk][tx * 4 + j];
            #pragma unroll
            for (int i = 0; i < 4; ++i)
                #pragma unroll
                for (int j = 0; j < 4; ++j)
                    acc[i][j] += a[i] * b[j];
        }
        __syncthreads();
    }

    #pragma unroll
    for (int i = 0; i < 4; ++i) {
        int m = m0 + ty * 4 + i;
        #pragma unroll
        for (int j = 0; j < 4; ++j) {
            int n = n0 + tx * 4 + j;
            float x = acc[i][j] + bias[n];
            if (ACT) x = (x > 0.f) ? (x + 1.f) : __expf(x);
            stf(&C[(size_t)m * N + n], x);
        }
    }
}

// ---------------------------------------------------------------------------
// Pass 1: per (bh, chunk): chunkS[d][k] = sum_t kp[t][d]*v[t][k];
//         chunkZ[d] = sum_t qp[t][d]
__global__ __launch_bounds__(256) void chunk_state(
    const bf16* __restrict__ qp, const bf16* __restrict__ kp,
    const bf16* __restrict__ v,
    float* __restrict__ chunkS, float* __restrict__ chunkZ)
{
    __shared__ float kpT_s[64 * 68];
    __shared__ float qpT_s[64 * 68];
    __shared__ float v_s  [64 * 68];

    const int bh = blockIdx.x;        // n*16 + h
    const int c  = blockIdx.y;
    const int n  = bh >> 4, h = bh & 15;
    const int tid = threadIdx.x;
    const size_t rowbase = (size_t)n * LSEQ + (size_t)c * TCH;

    #pragma unroll
    for (int r = 0; r < 4; ++r) {
        int q = r * 256 + tid;          // 1024 quads
        int t = q >> 4, f4 = (q & 15) * 4;
        size_t g = (rowbase + t) * DM + h * HD + f4;
        ushort4 ku = *(const ushort4*)((const unsigned short*)kp + g);
        ushort4 qu = *(const ushort4*)((const unsigned short*)qp + g);
        ushort4 vu = *(const ushort4*)((const unsigned short*)v  + g);
        kpT_s[(f4+0)*68 + t] = u2f(ku.x);
        kpT_s[(f4+1)*68 + t] = u2f(ku.y);
        kpT_s[(f4+2)*68 + t] = u2f(ku.z);
        kpT_s[(f4+3)*68 + t] = u2f(ku.w);
        qpT_s[(f4+0)*68 + t] = u2f(qu.x);
        qpT_s[(f4+1)*68 + t] = u2f(qu.y);
        qpT_s[(f4+2)*68 + t] = u2f(qu.z);
        qpT_s[(f4+3)*68 + t] = u2f(qu.w);
        *(float4*)&v_s[t*68 + f4] = make_float4(u2f(vu.x), u2f(vu.y), u2f(vu.z), u2f(vu.w));
    }
    __syncthreads();

    const int d0 = (tid >> 4) * 4;
    const int k0 = (tid & 15) * 4;
    float4 acc[4] = {};
    for (int t0 = 0; t0 < TCH; t0 += 4) {
        float4 X[4], Y[4];
        #pragma unroll
        for (int j = 0; j < 4; ++j) X[j] = *(const float4*)&kpT_s[(d0+j)*68 + t0];
        #pragma unroll
        for (int j = 0; j < 4; ++j) Y[j] = *(const float4*)&v_s[(t0+j)*68 + k0];
        fma44(acc, X, Y);
    }
    float* Sout = chunkS + (((size_t)bh * NC + c) << 12);
    #pragma unroll
    for (int a = 0; a < 4; ++a)
        *(float4*)&Sout[(d0+a)*64 + k0] = acc[a];

    if (tid < 64) {
        float s = 0.f;
        for (int t0 = 0; t0 < TCH; t0 += 4) {
            float4 q4 = *(const float4*)&qpT_s[tid*68 + t0];
            s += q4.x + q4.y + q4.z + q4.w;
        }
        chunkZ[((size_t)bh * NC + c) * 64 + tid] = s;
    }
}

// ---------------------------------------------------------------------------
// Pass 2: in-place EXCLUSIVE prefix over chunks (state + Z)
__global__ __launch_bounds__(256) void prefix_state(
    float* __restrict__ chunkS, float* __restrict__ chunkZ)
{
    const int bh = blockIdx.x;
    const int elem = blockIdx.y * 256 + threadIdx.x;   // 0..4095
    float* p = chunkS + (((size_t)bh * NC) << 12) + elem;
    float run = 0.f;
    #pragma unroll
    for (int c = 0; c < NC; ++c) {
        float x = p[(size_t)c << 12];
        p[(size_t)c << 12] = run;
        run += x;
    }
    if (blockIdx.y == 0 && threadIdx.x < 64) {
        float* pz = chunkZ + (size_t)bh * NC * 64 + threadIdx.x;
        float rz = 0.f;
        for (int c = 0; c < NC; ++c) {
            float x = pz[c * 64];
            pz[c * 64] = rz;
            rz += x;
        }
    }
}

// ---------------------------------------------------------------------------
// Pass 3: att = (qp @ Sprefix + tril(qp @ kp^T) @ v) / (Zprefix + cumsum(qp))
__global__ __launch_bounds__(256) void chunk_attn(
    const bf16* __restrict__ qp, const bf16* __restrict__ kp,
    const bf16* __restrict__ v,
    const float* __restrict__ chunkS, const float* __restrict__ chunkZ,
    bf16* __restrict__ att)
{
    __shared__ float qp_s [64 * 68];
    __shared__ float kpT_s[64 * 68];
    __shared__ float spA_s[64 * 68];           // Sprefix, then reused for A
    __shared__ unsigned short v_s[64 * 68];    // bf16 bits

    const int bh = blockIdx.x;
    const int c  = blockIdx.y;
    const int n  = bh >> 4, h = bh & 15;
    const int tid = threadIdx.x;
    const size_t rowbase = (size_t)n * LSEQ + (size_t)c * TCH;
    const float* Sbase = chunkS + (((size_t)bh * NC + c) << 12);

    #pragma unroll
    for (int r = 0; r < 4; ++r) {
        int q = r * 256 + tid;
        int t = q >> 4, f4 = (q & 15) * 4;
        size_t g = (rowbase + t) * DM + h * HD + f4;
        ushort4 qu = *(const ushort4*)((const unsigned short*)qp + g);
        ushort4 ku = *(const ushort4*)((const unsigned short*)kp + g);
        ushort4 vu = *(const ushort4*)((const unsigned short*)v  + g);
        *(float4*)&qp_s[t*68 + f4] = make_float4(u2f(qu.x), u2f(qu.y), u2f(qu.z), u2f(qu.w));
        kpT_s[(f4+0)*68 + t] = u2f(ku.x);
        kpT_s[(f4+1)*68 + t] = u2f(ku.y);
        kpT_s[(f4+2)*68 + t] = u2f(ku.z);
        kpT_s[(f4+3)*68 + t] = u2f(ku.w);
        *(ushort4*)&v_s[t*68 + f4] = vu;
        float4 sp = *(const float4*)&Sbase[q * 4];
        *(float4*)&spA_s[(q >> 4)*68 + (q & 15)*4] = sp;
    }
    __syncthreads();

    const int t0 = (tid >> 4) * 4;   // 4 output rows
    const int k0 = (tid & 15) * 4;   // 4 output cols

    // out1 = qp @ Sprefix
    float4 acc[4] = {};
    for (int d0 = 0; d0 < HD; d0 += 4) {
        float4 X[4], Y[4];
        #pragma unroll
        for (int j = 0; j < 4; ++j) X[j] = *(const float4*)&qp_s[(t0+j)*68 + d0];
        #pragma unroll
        for (int j = 0; j < 4; ++j) Y[j] = *(const float4*)&spA_s[(d0+j)*68 + k0];
        fma44(acc, X, Y);
    }

    // Z = Zprefix + inclusive cumsum of qp[:, k0..k0+3]
    float4 run = *(const float4*)&chunkZ[((size_t)bh * NC + c) * 64 + k0];
    float4 Zr[4];
    for (int s = 0; s < t0; ++s) {
        float4 q4 = *(const float4*)&qp_s[s*68 + k0];
        run.x += q4.x; run.y += q4.y; run.z += q4.z; run.w += q4.w;
    }
    #pragma unroll
    for (int j = 0; j < 4; ++j) {
        float4 q4 = *(const float4*)&qp_s[(t0+j)*68 + k0];
        run.x += q4.x; run.y += q4.y; run.z += q4.z; run.w += q4.w;
        Zr[j] = run;
    }
    __syncthreads();   // everyone done reading Sprefix from spA_s

    // A = tril(qp @ kp^T): this thread computes rows t0..t0+3, cols s0..s0+3
    {
        const int s0 = k0;
        float4 a2[4] = {};
        for (int d0 = 0; d0 < HD; d0 += 4) {
            float4 X[4], Y[4];
            #pragma unroll
            for (int j = 0; j < 4; ++j) X[j] = *(const float4*)&qp_s[(t0+j)*68 + d0];
            #pragma unroll
            for (int j = 0; j < 4; ++j) Y[j] = *(const float4*)&kpT_s[(d0+j)*68 + s0];
            fma44(a2, X, Y);
        }
        #pragma unroll
        for (int a = 0; a < 4; ++a) {
            int t = t0 + a;
            if (s0 + 0 > t) a2[a].x = 0.f;
            if (s0 + 1 > t) a2[a].y = 0.f;
            if (s0 + 2 > t) a2[a].z = 0.f;
            if (s0 + 3 > t) a2[a].w = 0.f;
        }
        #pragma unroll
        for (int a = 0; a < 4; ++a)
            *(float4*)&spA_s[(t0+a)*68 + s0] = a2[a];
    }
    __syncthreads();

    // out2 = A @ v
    for (int s0 = 0; s0 < TCH; s0 += 4) {
        float4 X[4], Y[4];
        #pragma unroll
        for (int j = 0; j < 4; ++j) X[j] = *(const float4*)&spA_s[(t0+j)*68 + s0];
        #pragma unroll
        for (int j = 0; j < 4; ++j) {
            ushort4 u = *(const ushort4*)&v_s[(s0+j)*68 + k0];
            Y[j] = make_float4(u2f(u.x), u2f(u.y), u2f(u.z), u2f(u.w));
        }
        fma44(acc, X, Y);
    }

    // out = acc / Z, store bf16
    #pragma unroll
    for (int a = 0; a < 4; ++a) {
        float ox = acc[a].x / Zr[a].x;
        float oy = acc[a].y / Zr[a].y;
        float oz = acc[a].z / Zr[a].z;
        float ow = acc[a].w / Zr[a].w;
        ushort4 ou = make_ushort4(f2u(ox), f2u(oy), f2u(oz), f2u(ow));
        *(ushort4*)((unsigned short*)att + (rowbase + t0 + a) * DM + h * HD + k0) = ou;
    }
}

// ---------------------------------------------------------------------------
extern "C" void kernel_launch(void* const* d_in, const int* in_sizes, int n_in,
                              void* d_out, int out_size, void* d_ws, size_t ws_size,
                              hipStream_t stream)
{
    const float* queries = (const float*)d_in[0];
    const float* keys    = (const float*)d_in[1];
    const float* values  = (const float*)d_in[2];
    const float* Wq = (const float*)d_in[3];
    const float* bq = (const float*)d_in[4];
    const float* Wk = (const float*)d_in[5];
    const float* bk = (const float*)d_in[6];
    const float* Wv = (const float*)d_in[7];
    const float* bv = (const float*)d_in[8];
    const float* Wo = (const float*)d_in[9];
    const float* bo = (const float*)d_in[10];
    float* out = (float*)d_out;

    const size_t elems = (size_t)MROWS * DM;
    bf16* qp  = (bf16*)d_ws;
    bf16* kp  = qp + elems;
    bf16* vv  = kp + elems;
    bf16* att = vv + elems;
    float* chunkS = (float*)(att + elems);                 // 64*32*4096 f32
    float* chunkZ = chunkS + (size_t)64 * NC * 4096;       // AFTER all of chunkS
    // total ws use: 4*16.78MB (bf16) + 33.55MB + 0.52MB ≈ 101 MB

    dim3 gblk(MROWS / 64, DM / 64);
    gemm_bias_act<1, float, bf16><<<gblk, 256, 0, stream>>>(queries, Wq, bq, qp, MROWS, DM, DM);
    gemm_bias_act<1, float, bf16><<<gblk, 256, 0, stream>>>(keys,    Wk, bk, kp, MROWS, DM, DM);
    gemm_bias_act<0, float, bf16><<<gblk, 256, 0, stream>>>(values,  Wv, bv, vv, MROWS, DM, DM);

    chunk_state <<<dim3(64, NC), 256, 0, stream>>>(qp, kp, vv, chunkS, chunkZ);
    prefix_state<<<dim3(64, 16), 256, 0, stream>>>(chunkS, chunkZ);
    chunk_attn  <<<dim3(64, NC), 256, 0, stream>>>(qp, kp, vv, chunkS, chunkZ, att);

    gemm_bias_act<0, bf16, float><<<gblk, 256, 0, stream>>>(att, Wo, bo, out, MROWS, DM, DM);
}

// Round 5
// 386.437 us; speedup vs baseline: 5.8234x; 4.1204x over previous
//
#include <hip/hip_runtime.h>
#include <hip/hip_bf16.h>

typedef __hip_bfloat16 bf16;

#define N_B   4
#define LSEQ  2048
#define DM    1024
#define NH    16
#define HD    64
#define MROWS (N_B * LSEQ)   // 8192
#define TCH   64
#define NC    (LSEQ / TCH)   // 32 chunks

typedef short bf16x8 __attribute__((ext_vector_type(8)));   // 8 bf16 in 4 VGPRs
typedef float f32x4  __attribute__((ext_vector_type(4)));

__device__ __forceinline__ float u2f(unsigned short u){ return __uint_as_float(((unsigned)u) << 16); }
__device__ __forceinline__ unsigned short f2u(float x){
    bf16 h = __float2bfloat16(x);
    return *reinterpret_cast<unsigned short*>(&h);
}

__device__ __forceinline__ void g2l16(const void* g, void* l) {
    __builtin_amdgcn_global_load_lds(
        (const __attribute__((address_space(1))) unsigned int*)g,
        (__attribute__((address_space(3))) unsigned int*)l, 16, 0, 0);
}

// acc[a][.] += sum_j X[a].comp(j) * Y[j][.]
__device__ __forceinline__ void fma44(float4 acc[4], const float4 X[4], const float4 Y[4]){
    #pragma unroll
    for (int a = 0; a < 4; ++a){
        float4 xa = X[a];
        { float s = xa.x; float4 yj = Y[0];
          acc[a].x += s*yj.x; acc[a].y += s*yj.y; acc[a].z += s*yj.z; acc[a].w += s*yj.w; }
        { float s = xa.y; float4 yj = Y[1];
          acc[a].x += s*yj.x; acc[a].y += s*yj.y; acc[a].z += s*yj.z; acc[a].w += s*yj.w; }
        { float s = xa.z; float4 yj = Y[2];
          acc[a].x += s*yj.x; acc[a].y += s*yj.y; acc[a].z += s*yj.z; acc[a].w += s*yj.w; }
        { float s = xa.w; float4 yj = Y[3];
          acc[a].x += s*yj.x; acc[a].y += s*yj.y; acc[a].z += s*yj.z; acc[a].w += s*yj.w; }
    }
}

// ---------------------------------------------------------------------------
// fp32 -> bf16 elementwise convert (float4 / ushort4 vectorized)
__global__ __launch_bounds__(256) void cvt_f32_bf16(
    const float* __restrict__ x, bf16* __restrict__ y, int n4)
{
    int i = blockIdx.x * 256 + threadIdx.x;
    if (i < n4) {
        float4 v = ((const float4*)x)[i];
        ushort4 o = make_ushort4(f2u(v.x), f2u(v.y), f2u(v.z), f2u(v.w));
        ((ushort4*)y)[i] = o;
    }
}

// W [K=DM][N=DM] fp32 row-major -> Wt [N][K] bf16 row-major (64x64 LDS tile)
__global__ __launch_bounds__(256) void transpose_w(
    const float* __restrict__ W, bf16* __restrict__ Wt)
{
    __shared__ unsigned short t[64][65];
    const int n0 = blockIdx.x * 64;
    const int k0 = blockIdx.y * 64;
    #pragma unroll
    for (int i = 0; i < 16; ++i) {
        int e = i * 256 + threadIdx.x;     // 0..4095
        int r = e >> 6, c = e & 63;        // r = k-row, c = n-col (coalesced)
        t[c][r] = f2u(W[(size_t)(k0 + r) * DM + n0 + c]);
    }
    __syncthreads();
    #pragma unroll
    for (int i = 0; i < 16; ++i) {
        int e = i * 256 + threadIdx.x;
        int r = e >> 6, c = e & 63;        // r = n-row, c = k-col (coalesced)
        ((unsigned short*)Wt)[(size_t)(n0 + r) * DM + k0 + c] = t[r][c];
    }
}

// ---------------------------------------------------------------------------
// MFMA GEMM: C[M,N] = act(A[M,K] @ Bt[N,K]^T + bias[N]); ACT=1 -> elu(x)+1
// 128x128 tile, BK=32, 4 waves (2x2), 16x16x32 bf16 MFMA, global_load_lds w=16.
template <int ACT, typename TO>
__global__ __launch_bounds__(256) void gemm_mfma(
    const bf16* __restrict__ A, const bf16* __restrict__ Bt,
    const float* __restrict__ bias, TO* __restrict__ C,
    int M, int N, int K)
{
    __shared__ __align__(16) short As[128 * 32];
    __shared__ __align__(16) short Bs[128 * 32];

    const int tid  = threadIdx.x;
    const int m0   = blockIdx.x * 128;
    const int n0   = blockIdx.y * 128;
    const int wave = tid >> 6;
    const int lane = tid & 63;
    const int wm   = (wave >> 1) * 64;
    const int wn   = (wave & 1) * 64;
    const int quad = lane >> 4;
    const int l16  = lane & 15;

    f32x4 acc[4][4] = {};

    for (int k0 = 0; k0 < K; k0 += 32) {
        // stage A tile (128x32) and B tile (128x32) via direct-to-LDS DMA.
        // LDS dst must be wave-uniform base + lane*16: e = i*256+tid does that.
        #pragma unroll
        for (int i = 0; i < 2; ++i) {
            int e = i * 256 + tid;         // 0..511
            int row = e >> 2, kg = e & 3;  // 4 x 16B segments per 32-k row
            g2l16(A  + (size_t)(m0 + row) * K + k0 + kg * 8, As + e * 8);
            g2l16(Bt + (size_t)(n0 + row) * K + k0 + kg * 8, Bs + e * 8);
        }
        __syncthreads();   // compiler emits vmcnt(0) drain before barrier

        bf16x8 af[4], bf_[4];
        #pragma unroll
        for (int mi = 0; mi < 4; ++mi)
            af[mi] = *(const bf16x8*)&As[(wm + mi * 16 + l16) * 32 + quad * 8];
        #pragma unroll
        for (int ni = 0; ni < 4; ++ni)
            bf_[ni] = *(const bf16x8*)&Bs[(wn + ni * 16 + l16) * 32 + quad * 8];

        #pragma unroll
        for (int mi = 0; mi < 4; ++mi)
            #pragma unroll
            for (int ni = 0; ni < 4; ++ni)
                acc[mi][ni] = __builtin_amdgcn_mfma_f32_16x16x32_bf16(
                    af[mi], bf_[ni], acc[mi][ni], 0, 0, 0);

        __syncthreads();   // protect LDS from next iteration's staging
    }

    // Epilogue: C/D layout col = lane&15, row = quad*4 + reg
    #pragma unroll
    for (int ni = 0; ni < 4; ++ni) {
        int col = n0 + wn + ni * 16 + l16;
        float bv = bias[col];
        #pragma unroll
        for (int mi = 0; mi < 4; ++mi) {
            #pragma unroll
            for (int r = 0; r < 4; ++r) {
                int row = m0 + wm + mi * 16 + quad * 4 + r;
                float x = acc[mi][ni][r] + bv;
                if (ACT) x = (x > 0.f) ? (x + 1.f) : __expf(x);
                if constexpr (sizeof(TO) == 2)
                    ((bf16*)C)[(size_t)row * N + col] = __float2bfloat16(x);
                else
                    ((float*)C)[(size_t)row * N + col] = x;
            }
        }
    }
}

// ---------------------------------------------------------------------------
// Pass 1: per (bh, chunk): chunkS[d][k] = sum_t kp[t][d]*v[t][k];
//         chunkZ[d] = sum_t qp[t][d]
__global__ __launch_bounds__(256) void chunk_state(
    const bf16* __restrict__ qp, const bf16* __restrict__ kp,
    const bf16* __restrict__ v,
    float* __restrict__ chunkS, float* __restrict__ chunkZ)
{
    __shared__ float kpT_s[64 * 68];
    __shared__ float qpT_s[64 * 68];
    __shared__ float v_s  [64 * 68];

    const int bh = blockIdx.x;        // n*16 + h
    const int c  = blockIdx.y;
    const int n  = bh >> 4, h = bh & 15;
    const int tid = threadIdx.x;
    const size_t rowbase = (size_t)n * LSEQ + (size_t)c * TCH;

    #pragma unroll
    for (int r = 0; r < 4; ++r) {
        int q = r * 256 + tid;          // 1024 quads
        int t = q >> 4, f4 = (q & 15) * 4;
        size_t g = (rowbase + t) * DM + h * HD + f4;
        ushort4 ku = *(const ushort4*)((const unsigned short*)kp + g);
        ushort4 qu = *(const ushort4*)((const unsigned short*)qp + g);
        ushort4 vu = *(const ushort4*)((const unsigned short*)v  + g);
        kpT_s[(f4+0)*68 + t] = u2f(ku.x);
        kpT_s[(f4+1)*68 + t] = u2f(ku.y);
        kpT_s[(f4+2)*68 + t] = u2f(ku.z);
        kpT_s[(f4+3)*68 + t] = u2f(ku.w);
        qpT_s[(f4+0)*68 + t] = u2f(qu.x);
        qpT_s[(f4+1)*68 + t] = u2f(qu.y);
        qpT_s[(f4+2)*68 + t] = u2f(qu.z);
        qpT_s[(f4+3)*68 + t] = u2f(qu.w);
        *(float4*)&v_s[t*68 + f4] = make_float4(u2f(vu.x), u2f(vu.y), u2f(vu.z), u2f(vu.w));
    }
    __syncthreads();

    const int d0 = (tid >> 4) * 4;
    const int k0 = (tid & 15) * 4;
    float4 acc[4] = {};
    for (int t0 = 0; t0 < TCH; t0 += 4) {
        float4 X[4], Y[4];
        #pragma unroll
        for (int j = 0; j < 4; ++j) X[j] = *(const float4*)&kpT_s[(d0+j)*68 + t0];
        #pragma unroll
        for (int j = 0; j < 4; ++j) Y[j] = *(const float4*)&v_s[(t0+j)*68 + k0];
        fma44(acc, X, Y);
    }
    float* Sout = chunkS + (((size_t)bh * NC + c) << 12);
    #pragma unroll
    for (int a = 0; a < 4; ++a)
        *(float4*)&Sout[(d0+a)*64 + k0] = acc[a];

    if (tid < 64) {
        float s = 0.f;
        for (int t0 = 0; t0 < TCH; t0 += 4) {
            float4 q4 = *(const float4*)&qpT_s[tid*68 + t0];
            s += q4.x + q4.y + q4.z + q4.w;
        }
        chunkZ[((size_t)bh * NC + c) * 64 + tid] = s;
    }
}

// ---------------------------------------------------------------------------
// Pass 2: in-place EXCLUSIVE prefix over chunks (state + Z)
__global__ __launch_bounds__(256) void prefix_state(
    float* __restrict__ chunkS, float* __restrict__ chunkZ)
{
    const int bh = blockIdx.x;
    const int elem = blockIdx.y * 256 + threadIdx.x;   // 0..4095
    float* p = chunkS + (((size_t)bh * NC) << 12) + elem;
    float run = 0.f;
    #pragma unroll
    for (int c = 0; c < NC; ++c) {
        float x = p[(size_t)c << 12];
        p[(size_t)c << 12] = run;
        run += x;
    }
    if (blockIdx.y == 0 && threadIdx.x < 64) {
        float* pz = chunkZ + (size_t)bh * NC * 64 + threadIdx.x;
        float rz = 0.f;
        for (int c = 0; c < NC; ++c) {
            float x = pz[c * 64];
            pz[c * 64] = rz;
            rz += x;
        }
    }
}

// ---------------------------------------------------------------------------
// Pass 3: att = (qp @ Sprefix + tril(qp @ kp^T) @ v) / (Zprefix + cumsum(qp))
__global__ __launch_bounds__(256) void chunk_attn(
    const bf16* __restrict__ qp, const bf16* __restrict__ kp,
    const bf16* __restrict__ v,
    const float* __restrict__ chunkS, const float* __restrict__ chunkZ,
    bf16* __restrict__ att)
{
    __shared__ float qp_s [64 * 68];
    __shared__ float kpT_s[64 * 68];
    __shared__ float spA_s[64 * 68];           // Sprefix, then reused for A
    __shared__ unsigned short v_s[64 * 68];    // bf16 bits

    const int bh = blockIdx.x;
    const int c  = blockIdx.y;
    const int n  = bh >> 4, h = bh & 15;
    const int tid = threadIdx.x;
    const size_t rowbase = (size_t)n * LSEQ + (size_t)c * TCH;
    const float* Sbase = chunkS + (((size_t)bh * NC + c) << 12);

    #pragma unroll
    for (int r = 0; r < 4; ++r) {
        int q = r * 256 + tid;
        int t = q >> 4, f4 = (q & 15) * 4;
        size_t g = (rowbase + t) * DM + h * HD + f4;
        ushort4 qu = *(const ushort4*)((const unsigned short*)qp + g);
        ushort4 ku = *(const ushort4*)((const unsigned short*)kp + g);
        ushort4 vu = *(const ushort4*)((const unsigned short*)v  + g);
        *(float4*)&qp_s[t*68 + f4] = make_float4(u2f(qu.x), u2f(qu.y), u2f(qu.z), u2f(qu.w));
        kpT_s[(f4+0)*68 + t] = u2f(ku.x);
        kpT_s[(f4+1)*68 + t] = u2f(ku.y);
        kpT_s[(f4+2)*68 + t] = u2f(ku.z);
        kpT_s[(f4+3)*68 + t] = u2f(ku.w);
        *(ushort4*)&v_s[t*68 + f4] = vu;
        float4 sp = *(const float4*)&Sbase[q * 4];
        *(float4*)&spA_s[(q >> 4)*68 + (q & 15)*4] = sp;
    }
    __syncthreads();

    const int t0 = (tid >> 4) * 4;   // 4 output rows
    const int k0 = (tid & 15) * 4;   // 4 output cols

    // out1 = qp @ Sprefix
    float4 acc[4] = {};
    for (int d0 = 0; d0 < HD; d0 += 4) {
        float4 X[4], Y[4];
        #pragma unroll
        for (int j = 0; j < 4; ++j) X[j] = *(const float4*)&qp_s[(t0+j)*68 + d0];
        #pragma unroll
        for (int j = 0; j < 4; ++j) Y[j] = *(const float4*)&spA_s[(d0+j)*68 + k0];
        fma44(acc, X, Y);
    }

    // Z = Zprefix + inclusive cumsum of qp[:, k0..k0+3]
    float4 run = *(const float4*)&chunkZ[((size_t)bh * NC + c) * 64 + k0];
    float4 Zr[4];
    for (int s = 0; s < t0; ++s) {
        float4 q4 = *(const float4*)&qp_s[s*68 + k0];
        run.x += q4.x; run.y += q4.y; run.z += q4.z; run.w += q4.w;
    }
    #pragma unroll
    for (int j = 0; j < 4; ++j) {
        float4 q4 = *(const float4*)&qp_s[(t0+j)*68 + k0];
        run.x += q4.x; run.y += q4.y; run.z += q4.z; run.w += q4.w;
        Zr[j] = run;
    }
    __syncthreads();   // everyone done reading Sprefix from spA_s

    // A = tril(qp @ kp^T): rows t0..t0+3, cols s0..s0+3
    {
        const int s0 = k0;
        float4 a2[4] = {};
        for (int d0 = 0; d0 < HD; d0 += 4) {
            float4 X[4], Y[4];
            #pragma unroll
            for (int j = 0; j < 4; ++j) X[j] = *(const float4*)&qp_s[(t0+j)*68 + d0];
            #pragma unroll
            for (int j = 0; j < 4; ++j) Y[j] = *(const float4*)&kpT_s[(d0+j)*68 + s0];
            fma44(a2, X, Y);
        }
        #pragma unroll
        for (int a = 0; a < 4; ++a) {
            int t = t0 + a;
            if (s0 + 0 > t) a2[a].x = 0.f;
            if (s0 + 1 > t) a2[a].y = 0.f;
            if (s0 + 2 > t) a2[a].z = 0.f;
            if (s0 + 3 > t) a2[a].w = 0.f;
        }
        #pragma unroll
        for (int a = 0; a < 4; ++a)
            *(float4*)&spA_s[(t0+a)*68 + s0] = a2[a];
    }
    __syncthreads();

    // out2 = A @ v
    for (int s0 = 0; s0 < TCH; s0 += 4) {
        float4 X[4], Y[4];
        #pragma unroll
        for (int j = 0; j < 4; ++j) X[j] = *(const float4*)&spA_s[(t0+j)*68 + s0];
        #pragma unroll
        for (int j = 0; j < 4; ++j) {
            ushort4 u = *(const ushort4*)&v_s[(s0+j)*68 + k0];
            Y[j] = make_float4(u2f(u.x), u2f(u.y), u2f(u.z), u2f(u.w));
        }
        fma44(acc, X, Y);
    }

    // out = acc / Z, store bf16
    #pragma unroll
    for (int a = 0; a < 4; ++a) {
        float ox = acc[a].x / Zr[a].x;
        float oy = acc[a].y / Zr[a].y;
        float oz = acc[a].z / Zr[a].z;
        float ow = acc[a].w / Zr[a].w;
        ushort4 ou = make_ushort4(f2u(ox), f2u(oy), f2u(oz), f2u(ow));
        *(ushort4*)((unsigned short*)att + (rowbase + t0 + a) * DM + h * HD + k0) = ou;
    }
}

// ---------------------------------------------------------------------------
extern "C" void kernel_launch(void* const* d_in, const int* in_sizes, int n_in,
                              void* d_out, int out_size, void* d_ws, size_t ws_size,
                              hipStream_t stream)
{
    const float* queries = (const float*)d_in[0];
    const float* keys    = (const float*)d_in[1];
    const float* values  = (const float*)d_in[2];
    const float* Wq = (const float*)d_in[3];
    const float* bq = (const float*)d_in[4];
    const float* Wk = (const float*)d_in[5];
    const float* bk = (const float*)d_in[6];
    const float* Wv = (const float*)d_in[7];
    const float* bv = (const float*)d_in[8];
    const float* Wo = (const float*)d_in[9];
    const float* bo = (const float*)d_in[10];
    float* out = (float*)d_out;

    // Workspace layout (bytes). E2 = one [8192,1024] bf16 tensor.
    char* w = (char*)d_ws;
    const size_t E2 = (size_t)MROWS * DM * 2;   // 16,777,216
    const size_t WB = (size_t)DM * DM * 2;      //  2,097,152
    bf16* qb  = (bf16*)(w + 0 * E2);            // reused as att later
    bf16* kb  = (bf16*)(w + 1 * E2);            // reused (with vb) as chunkS
    bf16* vb  = (bf16*)(w + 2 * E2);
    bf16* Wqt = (bf16*)(w + 3 * E2 + 0 * WB);   // reused as chunkZ
    bf16* Wkt = (bf16*)(w + 3 * E2 + 1 * WB);
    bf16* Wvt = (bf16*)(w + 3 * E2 + 2 * WB);
    bf16* Wot = (bf16*)(w + 3 * E2 + 3 * WB);
    bf16* qp  = (bf16*)(w + 3 * E2 + 4 * WB);
    bf16* kp  = (bf16*)(w + 4 * E2 + 4 * WB);
    bf16* vv  = (bf16*)(w + 5 * E2 + 4 * WB);
    float* chunkS = (float*)kb;    // 33,554,432 B == kb+vb exactly
    float* chunkZ = (float*)Wqt;   //    524,288 B <= WB
    bf16*  att    = qb;
    // total footprint: 6*E2 + 4*WB ~= 109 MB

    const int n4 = (MROWS * DM) / 4;   // 2,097,152 quads
    cvt_f32_bf16<<<n4 / 256, 256, 0, stream>>>(queries, qb, n4);
    cvt_f32_bf16<<<n4 / 256, 256, 0, stream>>>(keys,    kb, n4);
    cvt_f32_bf16<<<n4 / 256, 256, 0, stream>>>(values,  vb, n4);

    dim3 tgrid(DM / 64, DM / 64);
    transpose_w<<<tgrid, 256, 0, stream>>>(Wq, Wqt);
    transpose_w<<<tgrid, 256, 0, stream>>>(Wk, Wkt);
    transpose_w<<<tgrid, 256, 0, stream>>>(Wv, Wvt);
    transpose_w<<<tgrid, 256, 0, stream>>>(Wo, Wot);

    dim3 ggrid(MROWS / 128, DM / 128);
    gemm_mfma<1, bf16><<<ggrid, 256, 0, stream>>>(qb, Wqt, bq, qp, MROWS, DM, DM);
    gemm_mfma<1, bf16><<<ggrid, 256, 0, stream>>>(kb, Wkt, bk, kp, MROWS, DM, DM);
    gemm_mfma<0, bf16><<<ggrid, 256, 0, stream>>>(vb, Wvt, bv, vv, MROWS, DM, DM);

    chunk_state <<<dim3(64, NC), 256, 0, stream>>>(qp, kp, vv, chunkS, chunkZ);
    prefix_state<<<dim3(64, 16), 256, 0, stream>>>(chunkS, chunkZ);
    chunk_attn  <<<dim3(64, NC), 256, 0, stream>>>(qp, kp, vv, chunkS, chunkZ, att);

    gemm_mfma<0, float><<<ggrid, 256, 0, stream>>>(att, Wot, bo, out, MROWS, DM, DM);
}

// Round 6
// 344.223 us; speedup vs baseline: 6.5376x; 1.1226x over previous
//
#include <hip/hip_runtime.h>
#include <hip/hip_bf16.h>

typedef __hip_bfloat16 bf16;

#define N_B   4
#define LSEQ  2048
#define DM    1024
#define NH    16
#define HD    64
#define MROWS (N_B * LSEQ)   // 8192
#define TCH   64
#define NC    (LSEQ / TCH)   // 32 chunks
#define PS    72             // LDS row stride (bf16 elems): 144 B = 16B-aligned, 2-way banks (free)

typedef short bf16x8 __attribute__((ext_vector_type(8)));   // 8 bf16 in 4 VGPRs
typedef float f32x4  __attribute__((ext_vector_type(4)));

__device__ __forceinline__ float u2f(unsigned short u){ return __uint_as_float(((unsigned)u) << 16); }
__device__ __forceinline__ unsigned short f2u(float x){
    bf16 h = __float2bfloat16(x);
    return *reinterpret_cast<unsigned short*>(&h);
}

__device__ __forceinline__ void g2l16(const void* g, void* l) {
    __builtin_amdgcn_global_load_lds(
        (const __attribute__((address_space(1))) unsigned int*)g,
        (__attribute__((address_space(3))) unsigned int*)l, 16, 0, 0);
}

// ---------------------------------------------------------------------------
// fp32 -> bf16 elementwise convert
__global__ __launch_bounds__(256) void cvt_f32_bf16(
    const float* __restrict__ x, bf16* __restrict__ y, int n4)
{
    int i = blockIdx.x * 256 + threadIdx.x;
    if (i < n4) {
        float4 v = ((const float4*)x)[i];
        ushort4 o = make_ushort4(f2u(v.x), f2u(v.y), f2u(v.z), f2u(v.w));
        ((ushort4*)y)[i] = o;
    }
}

// W [K=DM][N=DM] fp32 row-major -> Wt [N][K] bf16 row-major
__global__ __launch_bounds__(256) void transpose_w(
    const float* __restrict__ W, bf16* __restrict__ Wt)
{
    __shared__ unsigned short t[64][65];
    const int n0 = blockIdx.x * 64;
    const int k0 = blockIdx.y * 64;
    #pragma unroll
    for (int i = 0; i < 16; ++i) {
        int e = i * 256 + threadIdx.x;
        int r = e >> 6, c = e & 63;
        t[c][r] = f2u(W[(size_t)(k0 + r) * DM + n0 + c]);
    }
    __syncthreads();
    #pragma unroll
    for (int i = 0; i < 16; ++i) {
        int e = i * 256 + threadIdx.x;
        int r = e >> 6, c = e & 63;
        ((unsigned short*)Wt)[(size_t)(n0 + r) * DM + k0 + c] = t[r][c];
    }
}

// ---------------------------------------------------------------------------
// MFMA GEMM (unchanged from R5): C = act(A @ Bt^T + bias)
template <int ACT, typename TO>
__global__ __launch_bounds__(256) void gemm_mfma(
    const bf16* __restrict__ A, const bf16* __restrict__ Bt,
    const float* __restrict__ bias, TO* __restrict__ C,
    int M, int N, int K)
{
    __shared__ __align__(16) short As[128 * 32];
    __shared__ __align__(16) short Bs[128 * 32];

    const int tid  = threadIdx.x;
    const int m0   = blockIdx.x * 128;
    const int n0   = blockIdx.y * 128;
    const int wave = tid >> 6;
    const int lane = tid & 63;
    const int wm   = (wave >> 1) * 64;
    const int wn   = (wave & 1) * 64;
    const int quad = lane >> 4;
    const int l16  = lane & 15;

    f32x4 acc[4][4] = {};

    for (int k0 = 0; k0 < K; k0 += 32) {
        #pragma unroll
        for (int i = 0; i < 2; ++i) {
            int e = i * 256 + tid;
            int row = e >> 2, kg = e & 3;
            g2l16(A  + (size_t)(m0 + row) * K + k0 + kg * 8, As + e * 8);
            g2l16(Bt + (size_t)(n0 + row) * K + k0 + kg * 8, Bs + e * 8);
        }
        __syncthreads();

        bf16x8 af[4], bf_[4];
        #pragma unroll
        for (int mi = 0; mi < 4; ++mi)
            af[mi] = *(const bf16x8*)&As[(wm + mi * 16 + l16) * 32 + quad * 8];
        #pragma unroll
        for (int ni = 0; ni < 4; ++ni)
            bf_[ni] = *(const bf16x8*)&Bs[(wn + ni * 16 + l16) * 32 + quad * 8];

        #pragma unroll
        for (int mi = 0; mi < 4; ++mi)
            #pragma unroll
            for (int ni = 0; ni < 4; ++ni)
                acc[mi][ni] = __builtin_amdgcn_mfma_f32_16x16x32_bf16(
                    af[mi], bf_[ni], acc[mi][ni], 0, 0, 0);

        __syncthreads();
    }

    #pragma unroll
    for (int ni = 0; ni < 4; ++ni) {
        int col = n0 + wn + ni * 16 + l16;
        float bv = bias[col];
        #pragma unroll
        for (int mi = 0; mi < 4; ++mi) {
            #pragma unroll
            for (int r = 0; r < 4; ++r) {
                int row = m0 + wm + mi * 16 + quad * 4 + r;
                float x = acc[mi][ni][r] + bv;
                if (ACT) x = (x > 0.f) ? (x + 1.f) : __expf(x);
                if constexpr (sizeof(TO) == 2)
                    ((bf16*)C)[(size_t)row * N + col] = __float2bfloat16(x);
                else
                    ((float*)C)[(size_t)row * N + col] = x;
            }
        }
    }
}

// ---------------------------------------------------------------------------
// Pass 1 (MFMA): chunkS[d][k] = sum_t kp[t][d]*v[t][k];  chunkZ[d] = sum_t qp[t][d]
__global__ __launch_bounds__(256) void chunk_state(
    const bf16* __restrict__ qp, const bf16* __restrict__ kp,
    const bf16* __restrict__ v,
    float* __restrict__ chunkS, float* __restrict__ chunkZ)
{
    __shared__ __align__(16) unsigned short kpT_s[64 * PS];  // [d][t]
    __shared__ __align__(16) unsigned short vT_s [64 * PS];  // [k][t]
    __shared__ __align__(16) unsigned short qp_s [64 * PS];  // [t][d]
    __shared__ float red[4][64];

    const int bh = blockIdx.x;
    const int c  = blockIdx.y;
    const int n  = bh >> 4, h = bh & 15;
    const int tid = threadIdx.x;
    const size_t rowbase = (size_t)n * LSEQ + (size_t)c * TCH;

    #pragma unroll
    for (int r = 0; r < 4; ++r) {
        int q = r * 256 + tid;
        int t = q >> 4, c0 = (q & 15) * 4;
        size_t g = (rowbase + t) * DM + h * HD + c0;
        ushort4 ku = *(const ushort4*)((const unsigned short*)kp + g);
        ushort4 vu = *(const ushort4*)((const unsigned short*)v  + g);
        ushort4 qu = *(const ushort4*)((const unsigned short*)qp + g);
        kpT_s[(c0+0)*PS + t] = ku.x;  kpT_s[(c0+1)*PS + t] = ku.y;
        kpT_s[(c0+2)*PS + t] = ku.z;  kpT_s[(c0+3)*PS + t] = ku.w;
        vT_s [(c0+0)*PS + t] = vu.x;  vT_s [(c0+1)*PS + t] = vu.y;
        vT_s [(c0+2)*PS + t] = vu.z;  vT_s [(c0+3)*PS + t] = vu.w;
        *(ushort4*)&qp_s[t * PS + c0] = qu;
    }
    __syncthreads();

    const int wave = tid >> 6, lane = tid & 63;
    const int quad = lane >> 4, l16 = lane & 15;

    // Sc = kpT @ v : A[m=d][kd=t] = kpT_s, B[n=k][kd=t] = vT_s
    f32x4 acc[4] = {};
    #pragma unroll
    for (int kk = 0; kk < 2; ++kk) {
        bf16x8 af = *(const bf16x8*)&kpT_s[(wave*16 + l16) * PS + kk*32 + quad*8];
        #pragma unroll
        for (int ni = 0; ni < 4; ++ni) {
            bf16x8 bfr = *(const bf16x8*)&vT_s[(ni*16 + l16) * PS + kk*32 + quad*8];
            acc[ni] = __builtin_amdgcn_mfma_f32_16x16x32_bf16(af, bfr, acc[ni], 0, 0, 0);
        }
    }
    float* Sout = chunkS + (((size_t)bh * NC + c) << 12);
    #pragma unroll
    for (int ni = 0; ni < 4; ++ni) {
        int k = ni*16 + l16;
        #pragma unroll
        for (int r = 0; r < 4; ++r) {
            int d = wave*16 + quad*4 + r;
            Sout[d * 64 + k] = acc[ni][r];
        }
    }

    // chunkZ: column sums of qp
    {
        int d = tid & 63, part = tid >> 6;
        float s = 0.f;
        #pragma unroll
        for (int t = part*16; t < part*16 + 16; ++t)
            s += u2f(qp_s[t * PS + d]);
        red[part][d] = s;
    }
    __syncthreads();
    if (tid < 64)
        chunkZ[((size_t)bh * NC + c) * 64 + tid] =
            red[0][tid] + red[1][tid] + red[2][tid] + red[3][tid];
}

// ---------------------------------------------------------------------------
// Pass 2: exclusive prefix over chunks. Reads chunkS fp32, writes SpB bf16;
// chunkZ prefixed fp32 in place.
__global__ __launch_bounds__(256) void prefix_state(
    const float* __restrict__ chunkS, bf16* __restrict__ SpB,
    float* __restrict__ chunkZ)
{
    const int bh = blockIdx.x;
    const int elem = blockIdx.y * 256 + threadIdx.x;   // 0..4095
    const float* p = chunkS + (((size_t)bh * NC) << 12) + elem;
    unsigned short* o = (unsigned short*)SpB + (((size_t)bh * NC) << 12) + elem;
    float run = 0.f;
    #pragma unroll
    for (int c = 0; c < NC; ++c) {
        float x = p[(size_t)c << 12];
        o[(size_t)c << 12] = f2u(run);
        run += x;
    }
    if (blockIdx.y == 0 && threadIdx.x < 64) {
        float* pz = chunkZ + (size_t)bh * NC * 64 + threadIdx.x;
        float rz = 0.f;
        for (int c = 0; c < NC; ++c) {
            float x = pz[c * 64];
            pz[c * 64] = rz;
            rz += x;
        }
    }
}

// ---------------------------------------------------------------------------
// Pass 3 (MFMA): att = (qp@Sp + tril(qp@kp^T)@v) / (Zp + tril(1)@qp)
__global__ __launch_bounds__(256) void chunk_attn(
    const bf16* __restrict__ qp, const bf16* __restrict__ kp,
    const bf16* __restrict__ v, const bf16* __restrict__ SpB,
    const float* __restrict__ chunkZ, bf16* __restrict__ att)
{
    __shared__ __align__(16) unsigned short qp_s [64 * PS];  // [t][d]  A: out1,P
    __shared__ __align__(16) unsigned short kp_s [64 * PS];  // [s][d]  B: P
    __shared__ __align__(16) unsigned short SpT_s[64 * PS];  // [k][d]  B: out1
    __shared__ __align__(16) unsigned short vT_s [64 * PS];  // [k][s]  B: out2
    __shared__ __align__(16) unsigned short qpT_s[64 * PS];  // [k][s]  B: Zc
    __shared__ __align__(16) unsigned short P_s  [64 * PS];  // [t][s]  A: out2

    const int bh = blockIdx.x;
    const int c  = blockIdx.y;
    const int n  = bh >> 4, h = bh & 15;
    const int tid = threadIdx.x;
    const size_t rowbase = (size_t)n * LSEQ + (size_t)c * TCH;
    const unsigned short* Spb = (const unsigned short*)SpB + (((size_t)bh * NC + c) << 12);

    #pragma unroll
    for (int r = 0; r < 4; ++r) {
        int q = r * 256 + tid;
        int t = q >> 4, c0 = (q & 15) * 4;     // t = row (time or d), c0 = col base
        size_t g = (rowbase + t) * DM + h * HD + c0;
        ushort4 qu = *(const ushort4*)((const unsigned short*)qp + g);
        ushort4 ku = *(const ushort4*)((const unsigned short*)kp + g);
        ushort4 vu = *(const ushort4*)((const unsigned short*)v  + g);
        ushort4 su = *(const ushort4*)(Spb + q * 4);   // SpB row d=t, cols c0..c0+3
        *(ushort4*)&qp_s[t * PS + c0] = qu;
        *(ushort4*)&kp_s[t * PS + c0] = ku;
        vT_s [(c0+0)*PS + t] = vu.x;  vT_s [(c0+1)*PS + t] = vu.y;
        vT_s [(c0+2)*PS + t] = vu.z;  vT_s [(c0+3)*PS + t] = vu.w;
        qpT_s[(c0+0)*PS + t] = qu.x;  qpT_s[(c0+1)*PS + t] = qu.y;
        qpT_s[(c0+2)*PS + t] = qu.z;  qpT_s[(c0+3)*PS + t] = qu.w;
        SpT_s[(c0+0)*PS + t] = su.x;  SpT_s[(c0+1)*PS + t] = su.y;
        SpT_s[(c0+2)*PS + t] = su.z;  SpT_s[(c0+3)*PS + t] = su.w;
    }
    __syncthreads();

    const int wave = tid >> 6, lane = tid & 63;
    const int quad = lane >> 4, l16 = lane & 15;
    const int mrow = wave * 16;            // this wave's 16 output rows (t)

    f32x4 acc[4]  = {};   // out1 + out2
    f32x4 zacc[4] = {};   // Zc (intra-chunk inclusive cumsum of qp)
    f32x4 pacc[4] = {};   // P = qp @ kp^T

    const unsigned short ONE = 0x3F80;     // bf16 1.0

    #pragma unroll
    for (int kk = 0; kk < 2; ++kk) {
        bf16x8 af = *(const bf16x8*)&qp_s[(mrow + l16) * PS + kk*32 + quad*8];
        // tril A-frag: A[t=mrow+l16][s=kk*32+quad*8+j] = (s <= t)
        bf16x8 tf;
        #pragma unroll
        for (int j = 0; j < 8; ++j) {
            int s = kk*32 + quad*8 + j;
            tf[j] = (short)((s <= mrow + l16) ? ONE : 0);
        }
        #pragma unroll
        for (int ni = 0; ni < 4; ++ni) {
            int boff = (ni*16 + l16) * PS + kk*32 + quad*8;
            bf16x8 b_sp = *(const bf16x8*)&SpT_s[boff];
            bf16x8 b_kp = *(const bf16x8*)&kp_s [boff];
            bf16x8 b_qt = *(const bf16x8*)&qpT_s[boff];
            acc [ni] = __builtin_amdgcn_mfma_f32_16x16x32_bf16(af, b_sp, acc [ni], 0, 0, 0);
            pacc[ni] = __builtin_amdgcn_mfma_f32_16x16x32_bf16(af, b_kp, pacc[ni], 0, 0, 0);
            zacc[ni] = __builtin_amdgcn_mfma_f32_16x16x32_bf16(tf, b_qt, zacc[ni], 0, 0, 0);
        }
    }

    // mask P (keep s <= t) and round-trip to LDS in A-layout [t][s]
    #pragma unroll
    for (int ni = 0; ni < 4; ++ni) {
        int s = ni*16 + l16;
        #pragma unroll
        for (int r = 0; r < 4; ++r) {
            int t = mrow + quad*4 + r;
            float pv = (s <= t) ? pacc[ni][r] : 0.f;
            P_s[t * PS + s] = f2u(pv);
        }
    }
    __syncthreads();

    // out2 = P @ v
    #pragma unroll
    for (int kk = 0; kk < 2; ++kk) {
        bf16x8 af = *(const bf16x8*)&P_s[(mrow + l16) * PS + kk*32 + quad*8];
        #pragma unroll
        for (int ni = 0; ni < 4; ++ni) {
            bf16x8 b_v = *(const bf16x8*)&vT_s[(ni*16 + l16) * PS + kk*32 + quad*8];
            acc[ni] = __builtin_amdgcn_mfma_f32_16x16x32_bf16(af, b_v, acc[ni], 0, 0, 0);
        }
    }

    // epilogue: divide by Z = Zprefix[k] + Zc[t][k], store bf16
    #pragma unroll
    for (int ni = 0; ni < 4; ++ni) {
        int k = ni*16 + l16;
        float zp = chunkZ[((size_t)bh * NC + c) * 64 + k];
        #pragma unroll
        for (int r = 0; r < 4; ++r) {
            int t = mrow + quad*4 + r;
            float o = acc[ni][r] / (zp + zacc[ni][r]);
            ((unsigned short*)att)[(rowbase + t) * DM + h * HD + k] = f2u(o);
        }
    }
}

// ---------------------------------------------------------------------------
extern "C" void kernel_launch(void* const* d_in, const int* in_sizes, int n_in,
                              void* d_out, int out_size, void* d_ws, size_t ws_size,
                              hipStream_t stream)
{
    const float* queries = (const float*)d_in[0];
    const float* keys    = (const float*)d_in[1];
    const float* values  = (const float*)d_in[2];
    const float* Wq = (const float*)d_in[3];
    const float* bq = (const float*)d_in[4];
    const float* Wk = (const float*)d_in[5];
    const float* bk = (const float*)d_in[6];
    const float* Wv = (const float*)d_in[7];
    const float* bv = (const float*)d_in[8];
    const float* Wo = (const float*)d_in[9];
    const float* bo = (const float*)d_in[10];
    float* out = (float*)d_out;

    char* w = (char*)d_ws;
    const size_t E2 = (size_t)MROWS * DM * 2;   // 16,777,216
    const size_t WB = (size_t)DM * DM * 2;      //  2,097,152
    bf16* qb  = (bf16*)(w + 0 * E2);            // reused as att
    bf16* kb  = (bf16*)(w + 1 * E2);            // kb+vb reused as chunkS (fp32)
    bf16* vb  = (bf16*)(w + 2 * E2);
    bf16* Wqt = (bf16*)(w + 3 * E2 + 0 * WB);   // reused as chunkZ
    bf16* Wkt = (bf16*)(w + 3 * E2 + 1 * WB);
    bf16* Wvt = (bf16*)(w + 3 * E2 + 2 * WB);
    bf16* Wot = (bf16*)(w + 3 * E2 + 3 * WB);
    bf16* qp  = (bf16*)(w + 3 * E2 + 4 * WB);
    bf16* kp  = (bf16*)(w + 4 * E2 + 4 * WB);
    bf16* vv  = (bf16*)(w + 5 * E2 + 4 * WB);
    bf16* SpB = (bf16*)(w + 6 * E2 + 4 * WB);   // bf16 prefix state, 16.7 MB
    float* chunkS = (float*)kb;
    float* chunkZ = (float*)Wqt;
    bf16*  att    = qb;
    // footprint: 7*E2 + 4*WB ≈ 125.8 MB (≤134 MB proven in R1)

    const int n4 = (MROWS * DM) / 4;
    cvt_f32_bf16<<<n4 / 256, 256, 0, stream>>>(queries, qb, n4);
    cvt_f32_bf16<<<n4 / 256, 256, 0, stream>>>(keys,    kb, n4);
    cvt_f32_bf16<<<n4 / 256, 256, 0, stream>>>(values,  vb, n4);

    dim3 tgrid(DM / 64, DM / 64);
    transpose_w<<<tgrid, 256, 0, stream>>>(Wq, Wqt);
    transpose_w<<<tgrid, 256, 0, stream>>>(Wk, Wkt);
    transpose_w<<<tgrid, 256, 0, stream>>>(Wv, Wvt);
    transpose_w<<<tgrid, 256, 0, stream>>>(Wo, Wot);

    dim3 ggrid(MROWS / 128, DM / 128);
    gemm_mfma<1, bf16><<<ggrid, 256, 0, stream>>>(qb, Wqt, bq, qp, MROWS, DM, DM);
    gemm_mfma<1, bf16><<<ggrid, 256, 0, stream>>>(kb, Wkt, bk, kp, MROWS, DM, DM);
    gemm_mfma<0, bf16><<<ggrid, 256, 0, stream>>>(vb, Wvt, bv, vv, MROWS, DM, DM);

    chunk_state <<<dim3(64, NC), 256, 0, stream>>>(qp, kp, vv, chunkS, chunkZ);
    prefix_state<<<dim3(64, 16), 256, 0, stream>>>(chunkS, SpB, chunkZ);
    chunk_attn  <<<dim3(64, NC), 256, 0, stream>>>(qp, kp, vv, SpB, chunkZ, att);

    gemm_mfma<0, float><<<ggrid, 256, 0, stream>>>(att, Wot, bo, out, MROWS, DM, DM);
}

// Round 7
// 310.567 us; speedup vs baseline: 7.2460x; 1.1084x over previous
//
#include <hip/hip_runtime.h>
#include <hip/hip_bf16.h>

typedef __hip_bfloat16 bf16;

#define N_B   4
#define LSEQ  2048
#define DM    1024
#define NH    16
#define HD    64
#define MROWS (N_B * LSEQ)   // 8192
#define TCH   64
#define NC    (LSEQ / TCH)   // 32 chunks
#define PS    72             // LDS row stride (bf16 elems) for attn kernels

typedef short bf16x8 __attribute__((ext_vector_type(8)));
typedef float f32x4  __attribute__((ext_vector_type(4)));

__device__ __forceinline__ float u2f(unsigned short u){ return __uint_as_float(((unsigned)u) << 16); }
__device__ __forceinline__ unsigned short f2u(float x){
    bf16 h = __float2bfloat16(x);
    return *reinterpret_cast<unsigned short*>(&h);
}

__device__ __forceinline__ void g2l16(const void* g, void* l) {
    __builtin_amdgcn_global_load_lds(
        (const __attribute__((address_space(1))) unsigned int*)g,
        (__attribute__((address_space(3))) unsigned int*)l, 16, 0, 0);
}

// ---------------------------------------------------------------------------
// fused fp32 -> bf16 convert for 3 tensors (blockIdx.x / per selects tensor)
__global__ __launch_bounds__(256) void cvt3_f32_bf16(
    const float* __restrict__ x0, const float* __restrict__ x1, const float* __restrict__ x2,
    bf16* __restrict__ y0, bf16* __restrict__ y1, bf16* __restrict__ y2, int per)
{
    int which = blockIdx.x / per;
    const float* x = (which == 0) ? x0 : (which == 1) ? x1 : x2;
    bf16* y = (which == 0) ? y0 : (which == 1) ? y1 : y2;
    int i = (blockIdx.x - which * per) * 256 + threadIdx.x;
    float4 v = ((const float4*)x)[i];
    ushort4 o = make_ushort4(f2u(v.x), f2u(v.y), f2u(v.z), f2u(v.w));
    ((ushort4*)y)[i] = o;
}

// fused transpose for 4 weight matrices: W [K][N] fp32 -> Wt [N][K] bf16
__global__ __launch_bounds__(256) void transpose_w4(
    const float* __restrict__ W0, const float* __restrict__ W1,
    const float* __restrict__ W2, const float* __restrict__ W3,
    bf16* __restrict__ T0, bf16* __restrict__ T1,
    bf16* __restrict__ T2, bf16* __restrict__ T3)
{
    const int z = blockIdx.z;
    const float* W = (z == 0) ? W0 : (z == 1) ? W1 : (z == 2) ? W2 : W3;
    bf16* Wt = (z == 0) ? T0 : (z == 1) ? T1 : (z == 2) ? T2 : T3;

    __shared__ unsigned short t[64][65];
    const int n0 = blockIdx.x * 64;
    const int k0 = blockIdx.y * 64;
    #pragma unroll
    for (int i = 0; i < 16; ++i) {
        int e = i * 256 + threadIdx.x;
        int r = e >> 6, c = e & 63;
        t[c][r] = f2u(W[(size_t)(k0 + r) * DM + n0 + c]);
    }
    __syncthreads();
    #pragma unroll
    for (int i = 0; i < 16; ++i) {
        int e = i * 256 + threadIdx.x;
        int r = e >> 6, c = e & 63;
        ((unsigned short*)Wt)[(size_t)(n0 + r) * DM + k0 + c] = t[r][c];
    }
}

// ---------------------------------------------------------------------------
// MFMA GEMM, up to 3 problems in one launch (blockIdx.z selects).
// C = act(A @ Bt^T + bias), act per-z via actMask bit. XOR-swizzled LDS.
template <typename TO>
__global__ __launch_bounds__(256) void gemm_mfma3(
    const bf16* __restrict__ A0, const bf16* __restrict__ A1, const bf16* __restrict__ A2,
    const bf16* __restrict__ B0, const bf16* __restrict__ B1, const bf16* __restrict__ B2,
    const float* __restrict__ c0, const float* __restrict__ c1, const float* __restrict__ c2,
    TO* __restrict__ C0, TO* __restrict__ C1, TO* __restrict__ C2,
    int actMask, int M, int N, int K)
{
    const int z = blockIdx.z;
    const bf16* A  = (z == 0) ? A0 : (z == 1) ? A1 : A2;
    const bf16* Bt = (z == 0) ? B0 : (z == 1) ? B1 : B2;
    const float* bias = (z == 0) ? c0 : (z == 1) ? c1 : c2;
    TO* C = (z == 0) ? C0 : (z == 1) ? C1 : C2;
    const int act = (actMask >> z) & 1;

    __shared__ __align__(16) short As[128 * 32];
    __shared__ __align__(16) short Bs[128 * 32];

    const int tid  = threadIdx.x;
    const int m0   = blockIdx.x * 128;
    const int n0   = blockIdx.y * 128;
    const int wave = tid >> 6;
    const int lane = tid & 63;
    const int wm   = (wave >> 1) * 64;
    const int wn   = (wave & 1) * 64;
    const int quad = lane >> 4;
    const int l16  = lane & 15;
    const int ksw  = (quad ^ (l16 & 3)) * 8;   // swizzled k-group for frag reads

    f32x4 acc[4][4] = {};

    for (int k0i = 0; k0i < K; k0i += 32) {
        #pragma unroll
        for (int i = 0; i < 2; ++i) {
            int e = i * 256 + tid;
            int row = e >> 2, kg = e & 3;
            int kgs = (kg ^ (row & 3)) * 8;    // store global kg at swizzled slot
            g2l16(A  + (size_t)(m0 + row) * K + k0i + kgs, As + e * 8);
            g2l16(Bt + (size_t)(n0 + row) * K + k0i + kgs, Bs + e * 8);
        }
        __syncthreads();

        bf16x8 af[4], bf_[4];
        #pragma unroll
        for (int mi = 0; mi < 4; ++mi)
            af[mi] = *(const bf16x8*)&As[(wm + mi * 16 + l16) * 32 + ksw];
        #pragma unroll
        for (int ni = 0; ni < 4; ++ni)
            bf_[ni] = *(const bf16x8*)&Bs[(wn + ni * 16 + l16) * 32 + ksw];

        #pragma unroll
        for (int mi = 0; mi < 4; ++mi)
            #pragma unroll
            for (int ni = 0; ni < 4; ++ni)
                acc[mi][ni] = __builtin_amdgcn_mfma_f32_16x16x32_bf16(
                    af[mi], bf_[ni], acc[mi][ni], 0, 0, 0);

        __syncthreads();
    }

    #pragma unroll
    for (int ni = 0; ni < 4; ++ni) {
        int col = n0 + wn + ni * 16 + l16;
        float bv = bias[col];
        #pragma unroll
        for (int mi = 0; mi < 4; ++mi) {
            #pragma unroll
            for (int r = 0; r < 4; ++r) {
                int row = m0 + wm + mi * 16 + quad * 4 + r;
                float x = acc[mi][ni][r] + bv;
                if (act) x = (x > 0.f) ? (x + 1.f) : __expf(x);
                if constexpr (sizeof(TO) == 2)
                    ((bf16*)C)[(size_t)row * N + col] = __float2bfloat16(x);
                else
                    ((float*)C)[(size_t)row * N + col] = x;
            }
        }
    }
}

// ---------------------------------------------------------------------------
// Pass 1 (MFMA): chunkSB[d][k] = sum_t kp[t][d]*v[t][k] (bf16); chunkZ fp32
__global__ __launch_bounds__(256) void chunk_state(
    const bf16* __restrict__ qp, const bf16* __restrict__ kp,
    const bf16* __restrict__ v,
    bf16* __restrict__ chunkSB, float* __restrict__ chunkZ)
{
    __shared__ __align__(16) unsigned short kpT_s[64 * PS];
    __shared__ __align__(16) unsigned short vT_s [64 * PS];
    __shared__ __align__(16) unsigned short qp_s [64 * PS];
    __shared__ float red[4][64];

    const int bh = blockIdx.x;
    const int c  = blockIdx.y;
    const int n  = bh >> 4, h = bh & 15;
    const int tid = threadIdx.x;
    const size_t rowbase = (size_t)n * LSEQ + (size_t)c * TCH;

    #pragma unroll
    for (int r = 0; r < 4; ++r) {
        int q = r * 256 + tid;
        int t = q >> 4, c0 = (q & 15) * 4;
        size_t g = (rowbase + t) * DM + h * HD + c0;
        ushort4 ku = *(const ushort4*)((const unsigned short*)kp + g);
        ushort4 vu = *(const ushort4*)((const unsigned short*)v  + g);
        ushort4 qu = *(const ushort4*)((const unsigned short*)qp + g);
        kpT_s[(c0+0)*PS + t] = ku.x;  kpT_s[(c0+1)*PS + t] = ku.y;
        kpT_s[(c0+2)*PS + t] = ku.z;  kpT_s[(c0+3)*PS + t] = ku.w;
        vT_s [(c0+0)*PS + t] = vu.x;  vT_s [(c0+1)*PS + t] = vu.y;
        vT_s [(c0+2)*PS + t] = vu.z;  vT_s [(c0+3)*PS + t] = vu.w;
        *(ushort4*)&qp_s[t * PS + c0] = qu;
    }
    __syncthreads();

    const int wave = tid >> 6, lane = tid & 63;
    const int quad = lane >> 4, l16 = lane & 15;

    f32x4 acc[4] = {};
    #pragma unroll
    for (int kk = 0; kk < 2; ++kk) {
        bf16x8 af = *(const bf16x8*)&kpT_s[(wave*16 + l16) * PS + kk*32 + quad*8];
        #pragma unroll
        for (int ni = 0; ni < 4; ++ni) {
            bf16x8 bfr = *(const bf16x8*)&vT_s[(ni*16 + l16) * PS + kk*32 + quad*8];
            acc[ni] = __builtin_amdgcn_mfma_f32_16x16x32_bf16(af, bfr, acc[ni], 0, 0, 0);
        }
    }
    unsigned short* Sout = (unsigned short*)chunkSB + (((size_t)bh * NC + c) << 12);
    #pragma unroll
    for (int ni = 0; ni < 4; ++ni) {
        int k = ni*16 + l16;
        #pragma unroll
        for (int r = 0; r < 4; ++r) {
            int d = wave*16 + quad*4 + r;
            Sout[d * 64 + k] = f2u(acc[ni][r]);
        }
    }

    {
        int d = tid & 63, part = tid >> 6;
        float s = 0.f;
        #pragma unroll
        for (int t = part*16; t < part*16 + 16; ++t)
            s += u2f(qp_s[t * PS + d]);
        red[part][d] = s;
    }
    __syncthreads();
    if (tid < 64)
        chunkZ[((size_t)bh * NC + c) * 64 + tid] =
            red[0][tid] + red[1][tid] + red[2][tid] + red[3][tid];
}

// ---------------------------------------------------------------------------
// Pass 2: exclusive prefix over chunks (bf16 in, fp32 accumulate, bf16 out)
__global__ __launch_bounds__(256) void prefix_state(
    const bf16* __restrict__ chunkSB, bf16* __restrict__ SpB,
    float* __restrict__ chunkZ)
{
    const int bh = blockIdx.x;
    const int elem = blockIdx.y * 256 + threadIdx.x;   // 0..4095
    const unsigned short* p = (const unsigned short*)chunkSB + (((size_t)bh * NC) << 12) + elem;
    unsigned short* o = (unsigned short*)SpB + (((size_t)bh * NC) << 12) + elem;
    float run = 0.f;
    #pragma unroll
    for (int c = 0; c < NC; ++c) {
        float x = u2f(p[(size_t)c << 12]);
        o[(size_t)c << 12] = f2u(run);
        run += x;
    }
    if (blockIdx.y == 0 && threadIdx.x < 64) {
        float* pz = chunkZ + (size_t)bh * NC * 64 + threadIdx.x;
        float rz = 0.f;
        for (int c = 0; c < NC; ++c) {
            float x = pz[c * 64];
            pz[c * 64] = rz;
            rz += x;
        }
    }
}

// ---------------------------------------------------------------------------
// Pass 3 (MFMA): att = (qp@Sp + tril(qp@kp^T)@v) / (Zp + tril(1)@qp)
__global__ __launch_bounds__(256) void chunk_attn(
    const bf16* __restrict__ qp, const bf16* __restrict__ kp,
    const bf16* __restrict__ v, const bf16* __restrict__ SpB,
    const float* __restrict__ chunkZ, bf16* __restrict__ att)
{
    __shared__ __align__(16) unsigned short qp_s [64 * PS];
    __shared__ __align__(16) unsigned short kp_s [64 * PS];
    __shared__ __align__(16) unsigned short SpT_s[64 * PS];
    __shared__ __align__(16) unsigned short vT_s [64 * PS];
    __shared__ __align__(16) unsigned short qpT_s[64 * PS];
    __shared__ __align__(16) unsigned short P_s  [64 * PS];

    const int bh = blockIdx.x;
    const int c  = blockIdx.y;
    const int n  = bh >> 4, h = bh & 15;
    const int tid = threadIdx.x;
    const size_t rowbase = (size_t)n * LSEQ + (size_t)c * TCH;
    const unsigned short* Spb = (const unsigned short*)SpB + (((size_t)bh * NC + c) << 12);

    #pragma unroll
    for (int r = 0; r < 4; ++r) {
        int q = r * 256 + tid;
        int t = q >> 4, c0 = (q & 15) * 4;
        size_t g = (rowbase + t) * DM + h * HD + c0;
        ushort4 qu = *(const ushort4*)((const unsigned short*)qp + g);
        ushort4 ku = *(const ushort4*)((const unsigned short*)kp + g);
        ushort4 vu = *(const ushort4*)((const unsigned short*)v  + g);
        ushort4 su = *(const ushort4*)(Spb + q * 4);
        *(ushort4*)&qp_s[t * PS + c0] = qu;
        *(ushort4*)&kp_s[t * PS + c0] = ku;
        vT_s [(c0+0)*PS + t] = vu.x;  vT_s [(c0+1)*PS + t] = vu.y;
        vT_s [(c0+2)*PS + t] = vu.z;  vT_s [(c0+3)*PS + t] = vu.w;
        qpT_s[(c0+0)*PS + t] = qu.x;  qpT_s[(c0+1)*PS + t] = qu.y;
        qpT_s[(c0+2)*PS + t] = qu.z;  qpT_s[(c0+3)*PS + t] = qu.w;
        SpT_s[(c0+0)*PS + t] = su.x;  SpT_s[(c0+1)*PS + t] = su.y;
        SpT_s[(c0+2)*PS + t] = su.z;  SpT_s[(c0+3)*PS + t] = su.w;
    }
    __syncthreads();

    const int wave = tid >> 6, lane = tid & 63;
    const int quad = lane >> 4, l16 = lane & 15;
    const int mrow = wave * 16;

    f32x4 acc[4]  = {};
    f32x4 zacc[4] = {};
    f32x4 pacc[4] = {};

    const unsigned short ONE = 0x3F80;

    #pragma unroll
    for (int kk = 0; kk < 2; ++kk) {
        bf16x8 af = *(const bf16x8*)&qp_s[(mrow + l16) * PS + kk*32 + quad*8];
        bf16x8 tf;
        #pragma unroll
        for (int j = 0; j < 8; ++j) {
            int s = kk*32 + quad*8 + j;
            tf[j] = (short)((s <= mrow + l16) ? ONE : 0);
        }
        #pragma unroll
        for (int ni = 0; ni < 4; ++ni) {
            int boff = (ni*16 + l16) * PS + kk*32 + quad*8;
            bf16x8 b_sp = *(const bf16x8*)&SpT_s[boff];
            bf16x8 b_kp = *(const bf16x8*)&kp_s [boff];
            bf16x8 b_qt = *(const bf16x8*)&qpT_s[boff];
            acc [ni] = __builtin_amdgcn_mfma_f32_16x16x32_bf16(af, b_sp, acc [ni], 0, 0, 0);
            pacc[ni] = __builtin_amdgcn_mfma_f32_16x16x32_bf16(af, b_kp, pacc[ni], 0, 0, 0);
            zacc[ni] = __builtin_amdgcn_mfma_f32_16x16x32_bf16(tf, b_qt, zacc[ni], 0, 0, 0);
        }
    }

    #pragma unroll
    for (int ni = 0; ni < 4; ++ni) {
        int s = ni*16 + l16;
        #pragma unroll
        for (int r = 0; r < 4; ++r) {
            int t = mrow + quad*4 + r;
            float pv = (s <= t) ? pacc[ni][r] : 0.f;
            P_s[t * PS + s] = f2u(pv);
        }
    }
    __syncthreads();

    #pragma unroll
    for (int kk = 0; kk < 2; ++kk) {
        bf16x8 af = *(const bf16x8*)&P_s[(mrow + l16) * PS + kk*32 + quad*8];
        #pragma unroll
        for (int ni = 0; ni < 4; ++ni) {
            bf16x8 b_v = *(const bf16x8*)&vT_s[(ni*16 + l16) * PS + kk*32 + quad*8];
            acc[ni] = __builtin_amdgcn_mfma_f32_16x16x32_bf16(af, b_v, acc[ni], 0, 0, 0);
        }
    }

    #pragma unroll
    for (int ni = 0; ni < 4; ++ni) {
        int k = ni*16 + l16;
        float zp = chunkZ[((size_t)bh * NC + c) * 64 + k];
        #pragma unroll
        for (int r = 0; r < 4; ++r) {
            int t = mrow + quad*4 + r;
            float o = acc[ni][r] / (zp + zacc[ni][r]);
            ((unsigned short*)att)[(rowbase + t) * DM + h * HD + k] = f2u(o);
        }
    }
}

// ---------------------------------------------------------------------------
extern "C" void kernel_launch(void* const* d_in, const int* in_sizes, int n_in,
                              void* d_out, int out_size, void* d_ws, size_t ws_size,
                              hipStream_t stream)
{
    const float* queries = (const float*)d_in[0];
    const float* keys    = (const float*)d_in[1];
    const float* values  = (const float*)d_in[2];
    const float* Wq = (const float*)d_in[3];
    const float* bq = (const float*)d_in[4];
    const float* Wk = (const float*)d_in[5];
    const float* bk = (const float*)d_in[6];
    const float* Wv = (const float*)d_in[7];
    const float* bv = (const float*)d_in[8];
    const float* Wo = (const float*)d_in[9];
    const float* bo = (const float*)d_in[10];
    float* out = (float*)d_out;

    char* w = (char*)d_ws;
    const size_t E2 = (size_t)MROWS * DM * 2;   // 16,777,216
    const size_t WB = (size_t)DM * DM * 2;      //  2,097,152
    bf16* qb  = (bf16*)(w + 0 * E2);            // reused as att
    bf16* kb  = (bf16*)(w + 1 * E2);            // reused as chunkSB (bf16)
    bf16* vb  = (bf16*)(w + 2 * E2);
    bf16* Wqt = (bf16*)(w + 3 * E2 + 0 * WB);   // reused as chunkZ
    bf16* Wkt = (bf16*)(w + 3 * E2 + 1 * WB);
    bf16* Wvt = (bf16*)(w + 3 * E2 + 2 * WB);
    bf16* Wot = (bf16*)(w + 3 * E2 + 3 * WB);
    bf16* qp  = (bf16*)(w + 3 * E2 + 4 * WB);
    bf16* kp  = (bf16*)(w + 4 * E2 + 4 * WB);
    bf16* vv  = (bf16*)(w + 5 * E2 + 4 * WB);
    bf16* SpB = (bf16*)(w + 6 * E2 + 4 * WB);
    bf16*  chunkSB = kb;
    float* chunkZ  = (float*)Wqt;
    bf16*  att     = qb;

    const int n4 = (MROWS * DM) / 4;    // 2,097,152
    const int per = n4 / 256;           // 8192 blocks per tensor
    cvt3_f32_bf16<<<3 * per, 256, 0, stream>>>(queries, keys, values, qb, kb, vb, per);

    transpose_w4<<<dim3(DM / 64, DM / 64, 4), 256, 0, stream>>>(
        Wq, Wk, Wv, Wo, Wqt, Wkt, Wvt, Wot);

    // 3 projection GEMMs fused: z=0 q (elu+1), z=1 k (elu+1), z=2 v (none)
    gemm_mfma3<bf16><<<dim3(MROWS / 128, DM / 128, 3), 256, 0, stream>>>(
        qb, kb, vb, Wqt, Wkt, Wvt, bq, bk, bv, qp, kp, vv,
        0b011, MROWS, DM, DM);

    chunk_state <<<dim3(64, NC), 256, 0, stream>>>(qp, kp, vv, chunkSB, chunkZ);
    prefix_state<<<dim3(64, 16), 256, 0, stream>>>(chunkSB, SpB, chunkZ);
    chunk_attn  <<<dim3(64, NC), 256, 0, stream>>>(qp, kp, vv, SpB, chunkZ, att);

    gemm_mfma3<float><<<dim3(MROWS / 128, DM / 128, 1), 256, 0, stream>>>(
        att, att, att, Wot, Wot, Wot, bo, bo, bo, out, out, out,
        0, MROWS, DM, DM);
}